// Round 7
// baseline (284.433 us; speedup 1.0000x reference)
//
#include <hip/hip_runtime.h>
#include <hip/hip_bf16.h>
#include <stdint.h>

typedef __hip_bfloat16 bf16;
typedef __attribute__((ext_vector_type(8))) short short8;
typedef __attribute__((ext_vector_type(4))) short short4v;
typedef __attribute__((ext_vector_type(4))) float floatx4;

#define D_MODEL 1024
#define D_STATE 16
#define D_INNER 2048
#define DT_RANK 64
#define BB 2
#define LL 2048
#define BL (BB * LL)            // 4096 rows
#define XZ_LD (2 * D_INNER)     // 4096 (fallback path only)
#define DBL_LD (DT_RANK + 2 * D_STATE)  // 96
#define NCH 64                  // time chunks for parallel scan
#define TCH (LL / NCH)          // 32 steps per chunk

__device__ __forceinline__ bf16 f2b(float f) { return __float2bfloat16(f); }

// fast sigmoid / softplus via native v_exp/v_log/v_rcp (~3e-7 rel err)
__device__ __forceinline__ float fsig(float v)  { return __fdividef(1.f, 1.f + __expf(-v)); }
__device__ __forceinline__ float fsoftp(float v){ return fmaxf(v, 0.f) + __logf(1.f + __expf(-fabsf(v))); }

// async 16B global -> LDS (wave-uniform LDS base + lane*16; rows contiguous)
__device__ __forceinline__ void gload16(const void* g, void* l) {
    __builtin_amdgcn_global_load_lds(
        (const __attribute__((address_space(1))) uint32_t*)(uintptr_t)g,
        (__attribute__((address_space(3))) uint32_t*)(uintptr_t)l,
        16, 0, 0);
}

#define S0 (4096 * 1024)   // W_in
#define S1 (128 * 2048)    // W_xproj padded to 128 rows
#define S2 (2048 * 64)     // W_dt
#define S3 (1024 * 2048)   // W_out
#define S4 (BL * DBL_LD)   // dbl zero-init (for split-K atomics)
#define WCVT_TOT (S0 + S1 + S2 + S3 + S4)
#define WCVT4 (WCVT_TOT / 4)   // quads -> 6912 blocks

// R24: vectorized fp32->bf16 quad convert (G13)
__device__ __forceinline__ void cvt4(const float* __restrict__ src,
                                     bf16* __restrict__ dst, int qi) {
    const floatx4 v = *(const floatx4*)(src + (size_t)qi * 4);
    short4v o;
#pragma unroll
    for (int j = 0; j < 4; ++j) {
        bf16 h = f2b(v[j]);
        unsigned short us;
        __builtin_memcpy(&us, &h, 2);
        o[j] = (short)us;
    }
    *(short4v*)(dst + (size_t)qi * 4) = o;
}

// ------- fused prep: LN (blocks 0..BL-1) + vectorized weight cvt ------------
__global__ __launch_bounds__(256) void prep_kernel(
    const float* __restrict__ x, const float* __restrict__ w,
    const float* __restrict__ b, bf16* __restrict__ xnb,
    const float* __restrict__ Win, const float* __restrict__ Wx,
    const float* __restrict__ Wdt, const float* __restrict__ Wout,
    bf16* __restrict__ win_bf, bf16* __restrict__ wx_bf,
    bf16* __restrict__ wdt_bf, bf16* __restrict__ wout_bf,
    float* __restrict__ dbl)
{
    __shared__ float s1[256], s2[256];
    const int tid = threadIdx.x;
    if (blockIdx.x < BL) {
        const int row = blockIdx.x;
        const float* xr = x + (size_t)row * D_MODEL;
        float v[4], sum = 0.f, sq = 0.f;
#pragma unroll
        for (int i = 0; i < 4; ++i) {
            v[i] = xr[tid + 256 * i];
            sum += v[i];
            sq  += v[i] * v[i];
        }
        s1[tid] = sum; s2[tid] = sq;
        __syncthreads();
        for (int s = 128; s > 0; s >>= 1) {
            if (tid < s) { s1[tid] += s1[tid + s]; s2[tid] += s2[tid + s]; }
            __syncthreads();
        }
        const float mu  = s1[0] * (1.f / D_MODEL);
        const float var = s2[0] * (1.f / D_MODEL) - mu * mu;
        const float rs  = rsqrtf(var + 1e-5f);
#pragma unroll
        for (int i = 0; i < 4; ++i) {
            const int c = tid + 256 * i;
            xnb[(size_t)row * D_MODEL + c] = f2b((v[i] - mu) * rs * w[c] + b[c]);
        }
    } else {
        int id = (blockIdx.x - BL) * 256 + tid;    // quad index
        if (id < S0 / 4) { cvt4(Win, win_bf, id); return; }
        id -= S0 / 4;
        if (id < S1 / 4) {
            if (id < (96 * 2048) / 4) cvt4(Wx, wx_bf, id);
            else *(short4v*)(wx_bf + (size_t)id * 4) = (short4v){0, 0, 0, 0};
            return;
        }
        id -= S1 / 4;
        if (id < S2 / 4) { cvt4(Wdt, wdt_bf, id); return; }
        id -= S2 / 4;
        if (id < S3 / 4) { cvt4(Wout, wout_bf, id); return; }
        id -= S3 / 4;
        *(floatx4*)(dbl + (size_t)id * 4) = (floatx4){0.f, 0.f, 0.f, 0.f};
    }
}

// ===== bf16 MFMA GEMM, compile-time-specialized epilogues (R17-proven) =======
// EPI: 3=atomicAdd (split-K, cheap per R24 postmortem); 5=softplus bf16.
#define GTM 128
#define GTN 128
#define GTK 32

template <int EPI>
__global__ __launch_bounds__(256) void gemm_t(
    const bf16* __restrict__ A, int lda,
    const bf16* __restrict__ B, int ldb,
    float* __restrict__ C, int ldc,
    int N, int K,
    const float* __restrict__ bias,
    bf16* __restrict__ C2)
{
    __shared__ short As[GTM * GTK];   // 8 KB
    __shared__ short Bs[GTN * GTK];   // 8 KB
    const int tid  = threadIdx.x;
    const int lane = tid & 63;
    const int wave = tid >> 6;            // 0..3
    const int wm = (wave & 1) * 64;
    const int wn = (wave >> 1) * 64;
    const int bm = blockIdx.y * GTM;
    const int bn = blockIdx.x * GTN;
    const int kbase = blockIdx.z * K;     // split-K base (K = slice length)

    floatx4 acc[4][4];
#pragma unroll
    for (int i = 0; i < 4; ++i)
#pragma unroll
        for (int j = 0; j < 4; ++j) acc[i][j] = (floatx4){0.f, 0.f, 0.f, 0.f};

    const int srow = wave * 16 + (lane >> 2);   // 0..63 (per pass)
    const int scol = (lane & 3) * 8;            // bf16 col within k-tile
    const int fm = lane & 15;
    const int q  = lane >> 4;

    for (int k0 = 0; k0 < K; k0 += GTK) {
#pragma unroll
        for (int r = 0; r < 2; ++r) {
            const int m = r * 64 + srow;
            gload16(A + (size_t)(bm + m) * lda + kbase + k0 + scol,
                    As + m * GTK + scol);
            gload16(B + (size_t)(bn + m) * ldb + kbase + k0 + scol,
                    Bs + m * GTK + scol);
        }
        __syncthreads();

        short8 af[4], bfr[4];
#pragma unroll
        for (int i = 0; i < 4; ++i)
            af[i] = *(short8*)&As[(wm + i * 16 + fm) * GTK + q * 8];
#pragma unroll
        for (int j = 0; j < 4; ++j)
            bfr[j] = *(short8*)&Bs[(wn + j * 16 + fm) * GTK + q * 8];
#pragma unroll
        for (int i = 0; i < 4; ++i)
#pragma unroll
            for (int j = 0; j < 4; ++j)
                acc[i][j] = __builtin_amdgcn_mfma_f32_16x16x32_bf16(
                    af[i], bfr[j], acc[i][j], 0, 0, 0);
        __syncthreads();
    }

    // C/D layout: col=lane&15, row=(lane>>4)*4+reg  [m89/m91-verified]
    const int col = lane & 15;
    const int rq  = (lane >> 4) * 4;
#pragma unroll
    for (int i = 0; i < 4; ++i) {
#pragma unroll
        for (int j = 0; j < 4; ++j) {
#pragma unroll
            for (int r = 0; r < 4; ++r) {
                const int gm = bm + wm + i * 16 + rq + r;
                const int gn = bn + wn + j * 16 + col;
                if (gn >= N) continue;
                float v = acc[i][j][r];
                if constexpr (EPI == 3) {
                    atomicAdd(&C[(size_t)gm * ldc + gn], v);
                } else if constexpr (EPI == 4) {
                    if (gn < D_INNER) C[(size_t)gm * ldc + gn] = v;
                    else C2[(size_t)gm * (size_t)D_INNER + (gn - D_INNER)] = f2b(v);
                } else {  // EPI == 5
                    C2[(size_t)gm * ldc + gn] = f2b(fsoftp(v + bias[gn]));
                }
            }
        }
    }
}

// ===== R25: G2 as 256x128 / BK=32 / 2-blocks-per-CU counted-vmcnt ============
// VGPR-occupancy model from R21/R23 counters: counted-vmcnt pipelining pays
// ONLY at 2 blocks/CU (gemm_out8: 84 unified regs -> 2/CU, helped; gemm256:
// 232 regs -> 1/CU, hurt; gemm128: 2/CU but FETCH 95 MB). 256x128/BK=32 is
// the corner satisfying both: acc[4][4]=64 AGPR + ~50 VGPR <= 128-class,
// LDS 48 KiB, A panels stay 256-row (per-XCD L2-resident via swizzle).
// Schedule = gemm_out8's proven pattern: issue 3 gloads for tile kt+1 at
// tile top, vmcnt(3) (= tile kt's only), barrier, 16 MFMA, barrier.
#define UNT (D_MODEL / 32)     // 32 K-tiles

__global__ __launch_bounds__(512, 4) void gemm_uz2(
    const bf16* __restrict__ A,   // xn_bf [4096 x 1024]
    const bf16* __restrict__ B,   // win_bf [4096 x 1024]
    float* __restrict__ U,        // uraw  [4096 x 2048]
    bf16* __restrict__ Z)         // zbf   [4096 x 2048]
{
    // A: dbuf d at d*8192 shorts (256 x 32); B: 16384 + d*4096 (128 x 32).
    __shared__ __attribute__((aligned(16))) short lds[24576];   // 48 KiB
    const int t    = threadIdx.x;
    const int lane = t & 63;
    const int wid  = t >> 6;        // 0..7
    const int wm   = wid >> 1;      // 0..3: 64-row block of the 256-row tile
    const int wn   = wid & 1;       // 0..1: 64-col half of the 128-col tile
    const int fm   = lane & 15;
    const int q    = lane >> 4;

    // bijective XCD swizzle: 512 blocks; XCD j gets 64 consecutive nids =
    // 2 bm-panels x 32 bn -> A panels (1 MB) L2-resident per XCD.
    const int lin = (int)blockIdx.x;
    const int nid = (lin & 7) * 64 + (lin >> 3);
    const int bm  = (nid >> 5) * 256;
    const int bn  = (nid & 31) * 128;

    // staging: thread t covers tile-row (t>>2)+p*128, slot (t&3);
    // global col-slot pre-swizzled: (t&3) ^ (row&3)  (p*128 ≡ 0 mod 4)
    const int sg = (((t & 3) ^ ((t >> 2) & 3)) << 3);   // shorts
    const short* Agp = (const short*)A + (size_t)(bm + (t >> 2)) * D_MODEL + sg;
    const short* Bgp = (const short*)B + (size_t)(bn + (t >> 2)) * D_MODEL + sg;

#define USTG(koff, d) do { \
        gload16(Agp + (koff),                        &lds[(d) * 8192 + t * 8]);        \
        gload16(Agp + (size_t)128 * D_MODEL + (koff), &lds[(d) * 8192 + 4096 + t * 8]); \
        gload16(Bgp + (koff),                        &lds[16384 + (d) * 4096 + t * 8]); \
    } while (0)

    // fragment-read swizzled slot (shorts): slot q ^ (row&3), row&3 == fm&3
    const int ss = ((q ^ (fm & 3)) << 3);

    floatx4 acc[4][4];
#pragma unroll
    for (int i = 0; i < 4; ++i)
#pragma unroll
        for (int j = 0; j < 4; ++j) acc[i][j] = (floatx4){0.f, 0.f, 0.f, 0.f};

    // prologue: stage K-tile 0 into dbuf 0 (3 loads)
    USTG(0, 0);

    for (int kt = 0; kt < UNT; ++kt) {
        const int d = kt & 1;
        if (kt + 1 < UNT) {
            USTG((kt + 1) * 32, d ^ 1);
            asm volatile("s_waitcnt vmcnt(3)" ::: "memory");   // tile kt staged
        } else {
            asm volatile("s_waitcnt vmcnt(0)" ::: "memory");
        }
        __builtin_amdgcn_s_barrier();    // block-wide: tile kt fully staged

        const short* Ab = &lds[d * 8192 + wm * 2048];           // 64 rows x 32
        const short* Bb = &lds[16384 + d * 4096 + wn * 2048];   // 64 rows x 32

        short8 af[4], bfr[4];
#pragma unroll
        for (int rf = 0; rf < 4; ++rf)
            af[rf] = *(const short8*)(Ab + (rf * 16 + fm) * 32 + ss);
#pragma unroll
        for (int cf = 0; cf < 4; ++cf)
            bfr[cf] = *(const short8*)(Bb + (cf * 16 + fm) * 32 + ss);

        __builtin_amdgcn_s_setprio(1);
#pragma unroll
        for (int rf = 0; rf < 4; ++rf)
#pragma unroll
            for (int cf = 0; cf < 4; ++cf)
                acc[rf][cf] = __builtin_amdgcn_mfma_f32_16x16x32_bf16(
                    af[rf], bfr[cf], acc[rf][cf], 0, 0, 0);
        __builtin_amdgcn_s_setprio(0);
        __builtin_amdgcn_s_barrier();    // guards next iter's dbuf overwrite
    }
#undef USTG

    // epilogue: C/D layout col=lane&15, row=(lane>>4)*4+reg; u/z split.
    // bn blocks are 128-wide and D_INNER%128==0 -> block never straddles.
    const int gm0 = bm + wm * 64 + q * 4;
    const int gn0 = bn + wn * 64 + fm;
    if (bn < D_INNER) {          // u half -> fp32
#pragma unroll
        for (int rf = 0; rf < 4; ++rf)
#pragma unroll
            for (int cf = 0; cf < 4; ++cf)
#pragma unroll
                for (int r = 0; r < 4; ++r)
                    U[(size_t)(gm0 + rf * 16 + r) * D_INNER + gn0 + cf * 16] =
                        acc[rf][cf][r];
    } else {                     // z half -> bf16
#pragma unroll
        for (int rf = 0; rf < 4; ++rf)
#pragma unroll
            for (int cf = 0; cf < 4; ++cf)
#pragma unroll
                for (int r = 0; r < 4; ++r)
                    Z[(size_t)(gm0 + rf * 16 + r) * D_INNER + gn0 + cf * 16 - D_INNER] =
                        f2b(acc[rf][cf][r]);
    }
}

// ===== R20/R21: G7-dedicated GEMM, counted-vmcnt deep pipeline ===============
// KEPT: 64 KiB LDS, 52 VGPR -> 2 blocks/CU; counted vmcnt(4) proven here.
#define ONT (D_INNER / 64)     // 32 K-tiles

__global__ __launch_bounds__(512, 2) void gemm_out8(
    const bf16* __restrict__ A,   // ucy [4096 x 2048]
    const bf16* __restrict__ B,   // wout_bf [1024 x 2048]
    const float* __restrict__ resid,
    float* __restrict__ C)        // out [4096 x 1024] fp32
{
    __shared__ __attribute__((aligned(16))) short lds[32768];
    const int t    = threadIdx.x;
    const int lane = t & 63;
    const int wid  = t >> 6;        // 0..7
    const int wm   = wid >> 2;
    const int wn   = wid & 3;
    const int fm   = lane & 15;
    const int q    = lane >> 4;

    const int lin = (int)blockIdx.x;
    const int nid = (lin & 7) * 32 + (lin >> 3);
    const int bm  = (nid >> 3) * 128;
    const int bn  = (nid & 7) * 128;

    const int sg   = (((t & 7) ^ ((t >> 3) & 7)) << 3);
    const int ldst = t * 8;
    const short* Agp = (const short*)A + (size_t)(bm + (t >> 3)) * D_INNER + sg;
    const short* Bgp = (const short*)B + (size_t)(bn + (t >> 3)) * D_INNER + sg;

#define OSTG(g, lb) do { \
        gload16((g),                        &lds[(lb) + ldst]);        \
        gload16((g) + (size_t)64 * D_INNER, &lds[(lb) + 4096 + ldst]); \
    } while (0)

    const int ss0 = ((q ^ (fm & 7)) << 3);
    const int ss1 = (((4 + q) ^ (fm & 7)) << 3);
    const int fro = fm * 64;

    floatx4 acc[4][2];
#pragma unroll
    for (int i = 0; i < 4; ++i)
#pragma unroll
        for (int j = 0; j < 2; ++j) acc[i][j] = (floatx4){0.f, 0.f, 0.f, 0.f};

    OSTG(Agp, 0);
    OSTG(Bgp, 16384);

    for (int kt = 0; kt < ONT; ++kt) {
        const int d = kt & 1;
        if (kt + 1 < ONT) {
            const int kn = (kt + 1) * 64;
            const int nb = (d ^ 1) * 8192;
            OSTG(Agp + kn, nb);
            OSTG(Bgp + kn, 16384 + nb);
            asm volatile("s_waitcnt vmcnt(4)" ::: "memory");
        } else {
            asm volatile("s_waitcnt vmcnt(0)" ::: "memory");
        }
        __builtin_amdgcn_s_barrier();

        const short* Ab = &lds[d * 8192 + wm * 4096];
        const short* Bb = &lds[16384 + d * 8192 + wn * 2048];

        short8 bfr[2][2];
#pragma unroll
        for (int cf = 0; cf < 2; ++cf) {
            bfr[cf][0] = *(const short8*)(Bb + cf * 1024 + fro + ss0);
            bfr[cf][1] = *(const short8*)(Bb + cf * 1024 + fro + ss1);
        }

#pragma unroll
        for (int qd = 0; qd < 2; ++qd) {
            short8 af[2][2];
#pragma unroll
            for (int i = 0; i < 2; ++i) {
                af[i][0] = *(const short8*)(Ab + (qd * 2 + i) * 1024 + fro + ss0);
                af[i][1] = *(const short8*)(Ab + (qd * 2 + i) * 1024 + fro + ss1);
            }
            __builtin_amdgcn_s_barrier();
            __builtin_amdgcn_s_setprio(1);
#pragma unroll
            for (int i = 0; i < 2; ++i)
#pragma unroll
                for (int cf = 0; cf < 2; ++cf) {
                    acc[qd * 2 + i][cf] = __builtin_amdgcn_mfma_f32_16x16x32_bf16(
                        af[i][0], bfr[cf][0], acc[qd * 2 + i][cf], 0, 0, 0);
                    acc[qd * 2 + i][cf] = __builtin_amdgcn_mfma_f32_16x16x32_bf16(
                        af[i][1], bfr[cf][1], acc[qd * 2 + i][cf], 0, 0, 0);
                }
            __builtin_amdgcn_s_setprio(0);
            __builtin_amdgcn_s_barrier();
        }
    }
#undef OSTG

    const int gm0 = bm + wm * 64 + q * 4;
    const int gn0 = bn + wn * 32 + fm;
#pragma unroll
    for (int i = 0; i < 4; ++i)
#pragma unroll
        for (int cf = 0; cf < 2; ++cf)
#pragma unroll
            for (int r = 0; r < 4; ++r) {
                const size_t idx = (size_t)(gm0 + i * 16 + r) * D_MODEL + gn0 + cf * 16;
                C[idx] = acc[i][cf][r] + resid[idx];
            }
}

// ===== R20 conv+SiLU v2: rolling-window, float4, each element read once ======
#define CCH 128               // time chunks
#define CTC (LL / CCH)        // 16 steps per chunk

__global__ __launch_bounds__(256) void conv_v2(
    const float* __restrict__ uraw, const float* __restrict__ cw,
    const float* __restrict__ cb, bf16* __restrict__ ucb)
{
    const int blk = blockIdx.x;
    const int c  = blk & (CCH - 1);
    const int dg = (blk >> 7) & 1;
    const int b  = blk >> 8;
    const int d4 = dg * 1024 + threadIdx.x * 4;
    float w0[4], w1[4], w2[4], w3[4], bias[4];
#pragma unroll
    for (int j = 0; j < 4; ++j) {
        bias[j] = cb[d4 + j];
        w0[j] = cw[(d4 + j) * 4 + 0];
        w1[j] = cw[(d4 + j) * 4 + 1];
        w2[j] = cw[(d4 + j) * 4 + 2];
        w3[j] = cw[(d4 + j) * 4 + 3];
    }
    const size_t base = ((size_t)b * LL + (size_t)c * CTC) * D_INNER + d4;
    floatx4 x0 = {0.f, 0.f, 0.f, 0.f}, x1 = x0, x2 = x0;
    if (c > 0) {
        x0 = *(const floatx4*)(uraw + base - 3 * (size_t)D_INNER);
        x1 = *(const floatx4*)(uraw + base - 2 * (size_t)D_INNER);
        x2 = *(const floatx4*)(uraw + base - 1 * (size_t)D_INNER);
    }
#pragma unroll
    for (int tt = 0; tt < CTC; ++tt) {
        const floatx4 x3 = *(const floatx4*)(uraw + base + (size_t)tt * D_INNER);
        short4v o;
#pragma unroll
        for (int j = 0; j < 4; ++j) {
            float a = bias[j] + x0[j] * w0[j] + x1[j] * w1[j]
                              + x2[j] * w2[j] + x3[j] * w3[j];
            a = a * fsig(a);
            bf16 h = f2b(a);
            unsigned short us;
            __builtin_memcpy(&us, &h, 2);
            o[j] = (short)us;
        }
        *(short4v*)(ucb + base + (size_t)tt * D_INNER) = o;
        x0 = x1; x1 = x2; x2 = x3;
    }
}

// ------------- dbl[:, :64] -> bf16 dt_r copy for GEMM-5 ----------------------
__global__ __launch_bounds__(256) void cvt_dtr(
    const float* __restrict__ dbl, bf16* __restrict__ dtr_bf)
{
    const int id = blockIdx.x * 256 + threadIdx.x;  // m*64+r
    const int m = id >> 6, r = id & 63;
    dtr_bf[id] = f2b(dbl[(size_t)m * DBL_LD + r]);
}

// ------------------------------ 3-phase scan ---------------------------------
__global__ __launch_bounds__(256) void scan_p1(
    const bf16* __restrict__ uc, const bf16* __restrict__ dtb,
    const float* __restrict__ dbl, const float* __restrict__ A_log,
    float* __restrict__ Psum, float* __restrict__ Hloc)
{
    const int blk = blockIdx.x;
    const int d = (blk & 7) * 256 + threadIdx.x;
    const int c = (blk >> 3) & (NCH - 1);
    const int b = blk >> 9;                  // NCH=64 -> 9 bits below b
    float A[D_STATE], h[D_STATE];
    bool lin = true;
#pragma unroll
    for (int n = 0; n < D_STATE; ++n) {
        A[n] = -__expf(A_log[d * D_STATE + n]);
        lin = lin && (fabsf(A[n] + (float)(n + 1)) < 1e-3f);
        h[n] = 0.f;
    }
    const size_t row0 = (size_t)b * LL + c * TCH;
    const bf16* dtp = dtb + row0 * D_INNER + d;
    const bf16* up  = uc  + row0 * D_INNER + d;
    const float* Bp = dbl + row0 * DBL_LD + DT_RANK;
    float S = 0.f;
    if (lin) {
        for (int t = 0; t < TCH; ++t) {
            const float dtv = (float)dtp[(size_t)t * D_INNER];
            const float uv  = (float)up[(size_t)t * D_INNER];
            const float du  = dtv * uv;
            S += dtv;
            const float e1 = __expf(-dtv);
            float dA = 1.f;
#pragma unroll
            for (int n = 0; n < D_STATE; ++n) {
                dA *= e1;                       // e1^(n+1)
                h[n] = dA * h[n] + du * Bp[(size_t)t * DBL_LD + n];
            }
        }
    } else {
        for (int t = 0; t < TCH; ++t) {
            const float dtv = (float)dtp[(size_t)t * D_INNER];
            const float uv  = (float)up[(size_t)t * D_INNER];
            const float du  = dtv * uv;
            S += dtv;
#pragma unroll
            for (int n = 0; n < D_STATE; ++n)
                h[n] = __expf(dtv * A[n]) * h[n] + du * Bp[(size_t)t * DBL_LD + n];
        }
    }
    const size_t o = (((size_t)b * NCH + c) * D_INNER + d) * D_STATE;
    if (lin) {
        const float E1 = __expf(-S);
        float P = 1.f;
#pragma unroll
        for (int n = 0; n < D_STATE; ++n) {
            P *= E1;
            Psum[o + n] = P;
            Hloc[o + n] = h[n];
        }
    } else {
#pragma unroll
        for (int n = 0; n < D_STATE; ++n) {
            Psum[o + n] = __expf(S * A[n]);
            Hloc[o + n] = h[n];
        }
    }
}

__global__ __launch_bounds__(256) void scan_p2(
    float* __restrict__ Psum, const float* __restrict__ Hloc)
{
    const int id = blockIdx.x * 256 + threadIdx.x;
    const int dn = id & (D_INNER * D_STATE - 1);
    const int b  = id >> 15;
    float h = 0.f;
    for (int c = 0; c < NCH; ++c) {
        const size_t o = ((size_t)(b * NCH + c) * D_INNER * D_STATE) + dn;
        const float P  = Psum[o];
        const float hl = Hloc[o];
        Psum[o] = h;          // Hin for chunk c
        h = P * h + hl;
    }
}

// phase 3: replay; bf16 u (ucy), bf16 dt, bf16 z (zbf); y overwrites ucy
__global__ __launch_bounds__(256) void scan_p3b(
    bf16* __restrict__ ucy, const bf16* __restrict__ dtb,
    const float* __restrict__ dbl, const float* __restrict__ A_log,
    const float* __restrict__ Dw, const float* __restrict__ Hin,
    const bf16* __restrict__ zbf)
{
    const int blk = blockIdx.x;
    const int d = (blk & 7) * 256 + threadIdx.x;
    const int c = (blk >> 3) & (NCH - 1);
    const int b = blk >> 9;                  // NCH=64 -> 9 bits below b
    float A[D_STATE], h[D_STATE];
    const size_t o = (((size_t)b * NCH + c) * D_INNER + d) * D_STATE;
    bool lin = true;
#pragma unroll
    for (int n = 0; n < D_STATE; ++n) {
        A[n] = -__expf(A_log[d * D_STATE + n]);
        lin = lin && (fabsf(A[n] + (float)(n + 1)) < 1e-3f);
        h[n] = Hin[o + n];
    }
    const float Dd = Dw[d];
    const size_t row0 = (size_t)b * LL + c * TCH;
    const bf16* dtp = dtb + row0 * D_INNER + d;
    bf16*       uyp = ucy + row0 * D_INNER + d;     // u in, y out (same slot)
    const float* BCp = dbl + row0 * DBL_LD;
    const bf16* zp   = zbf + row0 * D_INNER + d;
    if (lin) {
        for (int t = 0; t < TCH; ++t) {
            const float dtv = (float)dtp[(size_t)t * D_INNER];
            const float uv  = (float)uyp[(size_t)t * D_INNER];
            const float du  = dtv * uv;
            float acc = uv * Dd;
            const float* Brow = BCp + (size_t)t * DBL_LD + DT_RANK;
            const float* Crow = Brow + D_STATE;
            const float e1 = __expf(-dtv);
            float dA = 1.f;
#pragma unroll
            for (int n = 0; n < D_STATE; ++n) {
                dA *= e1;                       // e1^(n+1)
                h[n] = dA * h[n] + du * Brow[n];
                acc += h[n] * Crow[n];
            }
            const float zv = (float)zp[(size_t)t * D_INNER];
            uyp[(size_t)t * D_INNER] = f2b(acc * zv * fsig(zv));
        }
    } else {
        for (int t = 0; t < TCH; ++t) {
            const float dtv = (float)dtp[(size_t)t * D_INNER];
            const float uv  = (float)uyp[(size_t)t * D_INNER];
            const float du  = dtv * uv;
            float acc = uv * Dd;
            const float* Brow = BCp + (size_t)t * DBL_LD + DT_RANK;
            const float* Crow = Brow + D_STATE;
#pragma unroll
            for (int n = 0; n < D_STATE; ++n) {
                h[n] = __expf(dtv * A[n]) * h[n] + du * Brow[n];
                acc += h[n] * Crow[n];
            }
            const float zv = (float)zp[(size_t)t * D_INNER];
            uyp[(size_t)t * D_INNER] = f2b(acc * zv * fsig(zv));
        }
    }
}

// ---------------- fallback (small ws): R4 sequential path --------------------
#define BM 128
#define BN 128
#define BK 8

__global__ __launch_bounds__(256) void ln_kernel(
    const float* __restrict__ x, const float* __restrict__ w,
    const float* __restrict__ b, float* __restrict__ xnf)
{
    __shared__ float s1[256], s2[256];
    const int row = blockIdx.x;
    const int tid = threadIdx.x;
    const float* xr = x + (size_t)row * D_MODEL;
    float v[4], sum = 0.f, sq = 0.f;
#pragma unroll
    for (int i = 0; i < 4; ++i) {
        v[i] = xr[tid + 256 * i];
        sum += v[i];
        sq  += v[i] * v[i];
    }
    s1[tid] = sum; s2[tid] = sq;
    __syncthreads();
    for (int s = 128; s > 0; s >>= 1) {
        if (tid < s) { s1[tid] += s1[tid + s]; s2[tid] += s2[tid + s]; }
        __syncthreads();
    }
    const float mu  = s1[0] * (1.f / D_MODEL);
    const float var = s2[0] * (1.f / D_MODEL) - mu * mu;
    const float rs  = rsqrtf(var + 1e-5f);
#pragma unroll
    for (int i = 0; i < 4; ++i) {
        const int c = tid + 256 * i;
        xnf[(size_t)row * D_MODEL + c] = (v[i] - mu) * rs * w[c] + b[c];
    }
}

__global__ __launch_bounds__(256) void gemm_bt(
    const float* __restrict__ A, int lda,
    const float* __restrict__ Bw,
    float* __restrict__ C, int ldc,
    int M, int N, int K, int epi,
    const float* __restrict__ bias,
    const float* __restrict__ resid)
{
    __shared__ float As[BK][BM + 1];
    __shared__ float Bs[BK][BN + 1];
    const int tx = threadIdx.x, ty = threadIdx.y;
    const int tid = ty * 16 + tx;
    const int bm = blockIdx.y * BM, bn = blockIdx.x * BN;
    float acc[8][8];
#pragma unroll
    for (int i = 0; i < 8; ++i)
#pragma unroll
        for (int j = 0; j < 8; ++j) acc[i][j] = 0.f;
    for (int k0 = 0; k0 < K; k0 += BK) {
#pragma unroll
        for (int i = tid; i < BM * BK; i += 256) {
            const int m = i / BK, kk = i % BK;
            As[kk][m] = A[(size_t)(bm + m) * lda + (k0 + kk)];
        }
#pragma unroll
        for (int i = tid; i < BN * BK; i += 256) {
            const int n = i / BK, kk = i % BK;
            const int gn = bn + n;
            Bs[kk][n] = (gn < N) ? Bw[(size_t)gn * K + (k0 + kk)] : 0.f;
        }
        __syncthreads();
#pragma unroll
        for (int kk = 0; kk < BK; ++kk) {
            float av[8], bv[8];
#pragma unroll
            for (int i = 0; i < 8; ++i) av[i] = As[kk][ty * 8 + i];
#pragma unroll
            for (int j = 0; j < 8; ++j) bv[j] = Bs[kk][tx * 8 + j];
#pragma unroll
            for (int i = 0; i < 8; ++i)
#pragma unroll
                for (int j = 0; j < 8; ++j) acc[i][j] += av[i] * bv[j];
        }
        __syncthreads();
    }
#pragma unroll
    for (int i = 0; i < 8; ++i) {
        const int gm = bm + ty * 8 + i;
#pragma unroll
        for (int j = 0; j < 8; ++j) {
            const int gn = bn + tx * 8 + j;
            if (gn >= N) continue;
            float v = acc[i][j];
            if (epi == 1) {
                v += bias[gn];
                v = fmaxf(v, 0.f) + log1pf(expf(-fabsf(v)));
            } else if (epi == 2) {
                v += resid[(size_t)gm * ldc + gn];
            }
            C[(size_t)gm * ldc + gn] = v;
        }
    }
}

__global__ __launch_bounds__(256) void conv_silu_kernel(
    float* __restrict__ xz, const float* __restrict__ cw,
    const float* __restrict__ cb)
{
    const int idx = blockIdx.x * 256 + threadIdx.x;
    const int b = idx >> 11, d = idx & (D_INNER - 1);
    const float w0 = cw[d * 4 + 0], w1 = cw[d * 4 + 1];
    const float w2 = cw[d * 4 + 2], w3 = cw[d * 4 + 3];
    const float bias = cb[d];
    float* u = xz + (size_t)b * LL * XZ_LD + d;
    float x0 = 0.f, x1 = 0.f, x2 = 0.f;
    for (int t = 0; t < LL; ++t) {
        const float x3 = u[(size_t)t * XZ_LD];
        const float c = bias + x0 * w0 + x1 * w1 + x2 * w2 + x3 * w3;
        u[(size_t)t * XZ_LD] = c / (1.f + expf(-c));
        x0 = x1; x1 = x2; x2 = x3;
    }
}

__global__ __launch_bounds__(256) void scan_kernel(
    float* __restrict__ xz, const float* __restrict__ dtb,
    const float* __restrict__ dbl,
    const float* __restrict__ A_log, const float* __restrict__ Dw)
{
    const int idx = blockIdx.x * 256 + threadIdx.x;
    const int b = idx >> 11, d = idx & (D_INNER - 1);
    float A[D_STATE], h[D_STATE];
#pragma unroll
    for (int n = 0; n < D_STATE; ++n) {
        A[n] = -expf(A_log[d * D_STATE + n]);
        h[n] = 0.f;
    }
    const float Dd = Dw[d];
    const float* dtp  = dtb + (size_t)b * LL * D_INNER + d;
    float*       up   = xz  + (size_t)b * LL * XZ_LD + d;
    const float* dblp = dbl + (size_t)b * LL * DBL_LD;
    for (int t = 0; t < LL; ++t) {
        const float dtv = dtp[(size_t)t * D_INNER];
        const float uv  = up[(size_t)t * XZ_LD];
        const float zv  = up[(size_t)t * XZ_LD + D_INNER];
        const float* Brow = dblp + (size_t)t * DBL_LD + DT_RANK;
        const float* Crow = Brow + D_STATE;
        const float du = dtv * uv;
        float acc = uv * Dd;
#pragma unroll
        for (int n = 0; n < D_STATE; ++n) {
            const float dA = expf(dtv * A[n]);
            h[n] = dA * h[n] + du * Brow[n];
            acc += h[n] * Crow[n];
        }
        const float sz = zv / (1.f + expf(-zv));
        up[(size_t)t * XZ_LD] = acc * sz;
    }
}

extern "C" void kernel_launch(void* const* d_in, const int* in_sizes, int n_in,
                              void* d_out, int out_size, void* d_ws, size_t ws_size,
                              hipStream_t stream)
{
    const float* x       = (const float*)d_in[0];
    const float* ln_w    = (const float*)d_in[1];
    const float* ln_b    = (const float*)d_in[2];
    const float* W_in    = (const float*)d_in[3];
    const float* conv_w  = (const float*)d_in[4];
    const float* conv_b  = (const float*)d_in[5];
    const float* W_xproj = (const float*)d_in[6];
    const float* W_dt    = (const float*)d_in[7];
    const float* b_dt    = (const float*)d_in[8];
    const float* A_log   = (const float*)d_in[9];
    const float* Dw      = (const float*)d_in[10];
    const float* W_out   = (const float*)d_in[11];
    float* out = (float*)d_out;

    // ws layout identical to R15-R18 (134.8 MiB, each size audited)
    float* wsf     = (float*)d_ws;
    bf16*  dtb_bf  = (bf16*)wsf;
    float* uraw    = wsf + 4194304;
    bf16*  zbf     = (bf16*)(wsf + 12582912);
    float* Psum    = wsf + 16777216;
    float* Hloc    = wsf + 20971520;
    float* dbl     = wsf + 25165824;
    bf16*  ucy     = (bf16*)(wsf + 25559040);
    bf16*  xn_bf   = (bf16*)(wsf + 29753344);
    bf16*  win_bf  = (bf16*)(wsf + 31850496);
    bf16*  wx_bf   = (bf16*)(wsf + 33947648);
    bf16*  wdt_bf  = (bf16*)(wsf + 34078720);
    bf16*  wout_bf = (bf16*)(wsf + 34144256);
    bf16*  dtr_bf  = (bf16*)(wsf + 35192832);
    const size_t need_big = (size_t)35323904 * sizeof(float);

    if (ws_size >= need_big) {
        // fused LN + vectorized weight cvt (+dbl zero) — one launch
        prep_kernel<<<BL + WCVT4 / 256, 256, 0, stream>>>(
            x, ln_w, ln_b, xn_bf,
            W_in, W_xproj, W_dt, W_out, win_bf, wx_bf, wdt_bf, wout_bf, dbl);
        // G2: [u|z] = xn @ W_in^T via 256x128/BK=32 2-blocks-per-CU kernel
        gemm_uz2<<<dim3(512), 512, 0, stream>>>(xn_bf, win_bf, uraw, zbf);
        // conv+SiLU v2: rolling-window float4, fp32 u -> bf16 uc
        conv_v2<<<BB * 2 * CCH, 256, 0, stream>>>(uraw, conv_w, conv_b, ucy);
        // G4: dbl += uc @ W_xproj^T  (N=96 pad 128, split-K=8)  [EPI=3 atomic]
        gemm_t<3><<<dim3(1, BL / GTM, 8), 256, 0, stream>>>(
            ucy, D_INNER, wx_bf, D_INNER, dbl, DBL_LD,
            DBL_LD, D_INNER / 8, nullptr, nullptr);
        cvt_dtr<<<BL * DT_RANK / 256, 256, 0, stream>>>(dbl, dtr_bf);
        // G5: dt = softplus(dt_r @ W_dt^T + b_dt), bf16 store  [EPI=5]
        gemm_t<5><<<dim3(D_INNER / GTN, BL / GTM, 1), 256, 0, stream>>>(
            dtr_bf, DT_RANK, wdt_bf, DT_RANK, nullptr, D_INNER,
            D_INNER, DT_RANK, b_dt, dtb_bf);
        // chunked scan, NCH=64 (exp-power fast path)
        scan_p1<<<BB * NCH * 8, 256, 0, stream>>>(
            ucy, dtb_bf, dbl, A_log, Psum, Hloc);
        scan_p2<<<BB * D_INNER * D_STATE / 256, 256, 0, stream>>>(Psum, Hloc);
        scan_p3b<<<BB * NCH * 8, 256, 0, stream>>>(
            ucy, dtb_bf, dbl, A_log, Dw, Psum, zbf);
        // G7: out = y @ W_out^T + x  via counted-vmcnt 128x128 kernel
        gemm_out8<<<dim3(256), 512, 0, stream>>>(ucy, wout_bf, x, out);
    } else {
        float* fdtb = wsf;
        float* fxn  = fdtb;
        float* fxz  = fdtb + (size_t)BL * D_INNER;
        float* fdbl = fxz + (size_t)BL * XZ_LD;
        ln_kernel<<<BL, 256, 0, stream>>>(x, ln_w, ln_b, fxn);
        dim3 blk(16, 16);
        gemm_bt<<<dim3(XZ_LD / BN, BL / BM), blk, 0, stream>>>(
            fxn, D_MODEL, W_in, fxz, XZ_LD, BL, XZ_LD, D_MODEL, 0, nullptr, nullptr);
        conv_silu_kernel<<<(BB * D_INNER) / 256, 256, 0, stream>>>(fxz, conv_w, conv_b);
        gemm_bt<<<dim3(1, BL / BM), blk, 0, stream>>>(
            fxz, XZ_LD, W_xproj, fdbl, DBL_LD, BL, DBL_LD, D_INNER, 0, nullptr, nullptr);
        gemm_bt<<<dim3(D_INNER / BN, BL / BM), blk, 0, stream>>>(
            fdbl, DBL_LD, W_dt, fdtb, D_INNER, BL, D_INNER, DT_RANK, 1, b_dt, nullptr);
        scan_kernel<<<(BB * D_INNER) / 256, 256, 0, stream>>>(fxz, fdtb, fdbl, A_log, Dw);
        gemm_bt<<<dim3(D_MODEL / BN, BL / BM), blk, 0, stream>>>(
            fxz, XZ_LD, W_out, out, D_MODEL, BL, D_MODEL, D_INNER, 2, nullptr, x);
    }
}

// Round 8
// 277.777 us; speedup vs baseline: 1.0240x; 1.0240x over previous
//
#include <hip/hip_runtime.h>
#include <hip/hip_bf16.h>
#include <stdint.h>

typedef __hip_bfloat16 bf16;
typedef __attribute__((ext_vector_type(8))) short short8;
typedef __attribute__((ext_vector_type(4))) short short4v;
typedef __attribute__((ext_vector_type(4))) float floatx4;

#define D_MODEL 1024
#define D_STATE 16
#define D_INNER 2048
#define DT_RANK 64
#define BB 2
#define LL 2048
#define BL (BB * LL)            // 4096 rows
#define XZ_LD (2 * D_INNER)     // 4096 (fallback path only)
#define DBL_LD (DT_RANK + 2 * D_STATE)  // 96
#define NCH 64                  // time chunks for parallel scan
#define TCH (LL / NCH)          // 32 steps per chunk

__device__ __forceinline__ bf16 f2b(float f) { return __float2bfloat16(f); }

// fast sigmoid / softplus via native v_exp/v_log/v_rcp (~3e-7 rel err)
__device__ __forceinline__ float fsig(float v)  { return __fdividef(1.f, 1.f + __expf(-v)); }
__device__ __forceinline__ float fsoftp(float v){ return fmaxf(v, 0.f) + __logf(1.f + __expf(-fabsf(v))); }

// async 16B global -> LDS (wave-uniform LDS base + lane*16; rows contiguous)
__device__ __forceinline__ void gload16(const void* g, void* l) {
    __builtin_amdgcn_global_load_lds(
        (const __attribute__((address_space(1))) uint32_t*)(uintptr_t)g,
        (__attribute__((address_space(3))) uint32_t*)(uintptr_t)l,
        16, 0, 0);
}

#define S0 (4096 * 1024)   // W_in
#define S1 (128 * 2048)    // W_xproj padded to 128 rows
#define S2 (2048 * 64)     // W_dt
#define S3 (1024 * 2048)   // W_out
#define S4 (BL * DBL_LD)   // dbl zero-init (for split-K atomics)
#define WCVT_TOT (S0 + S1 + S2 + S3 + S4)
#define WCVT4 (WCVT_TOT / 4)   // quads -> 6912 blocks

// R24: vectorized fp32->bf16 quad convert (G13)
__device__ __forceinline__ void cvt4(const float* __restrict__ src,
                                     bf16* __restrict__ dst, int qi) {
    const floatx4 v = *(const floatx4*)(src + (size_t)qi * 4);
    short4v o;
#pragma unroll
    for (int j = 0; j < 4; ++j) {
        bf16 h = f2b(v[j]);
        unsigned short us;
        __builtin_memcpy(&us, &h, 2);
        o[j] = (short)us;
    }
    *(short4v*)(dst + (size_t)qi * 4) = o;
}

// ------- fused prep: LN (blocks 0..BL-1) + vectorized weight cvt ------------
__global__ __launch_bounds__(256) void prep_kernel(
    const float* __restrict__ x, const float* __restrict__ w,
    const float* __restrict__ b, bf16* __restrict__ xnb,
    const float* __restrict__ Win, const float* __restrict__ Wx,
    const float* __restrict__ Wdt, const float* __restrict__ Wout,
    bf16* __restrict__ win_bf, bf16* __restrict__ wx_bf,
    bf16* __restrict__ wdt_bf, bf16* __restrict__ wout_bf,
    float* __restrict__ dbl)
{
    __shared__ float s1[256], s2[256];
    const int tid = threadIdx.x;
    if (blockIdx.x < BL) {
        const int row = blockIdx.x;
        const float* xr = x + (size_t)row * D_MODEL;
        float v[4], sum = 0.f, sq = 0.f;
#pragma unroll
        for (int i = 0; i < 4; ++i) {
            v[i] = xr[tid + 256 * i];
            sum += v[i];
            sq  += v[i] * v[i];
        }
        s1[tid] = sum; s2[tid] = sq;
        __syncthreads();
        for (int s = 128; s > 0; s >>= 1) {
            if (tid < s) { s1[tid] += s1[tid + s]; s2[tid] += s2[tid + s]; }
            __syncthreads();
        }
        const float mu  = s1[0] * (1.f / D_MODEL);
        const float var = s2[0] * (1.f / D_MODEL) - mu * mu;
        const float rs  = rsqrtf(var + 1e-5f);
#pragma unroll
        for (int i = 0; i < 4; ++i) {
            const int c = tid + 256 * i;
            xnb[(size_t)row * D_MODEL + c] = f2b((v[i] - mu) * rs * w[c] + b[c]);
        }
    } else {
        int id = (blockIdx.x - BL) * 256 + tid;    // quad index
        if (id < S0 / 4) { cvt4(Win, win_bf, id); return; }
        id -= S0 / 4;
        if (id < S1 / 4) {
            if (id < (96 * 2048) / 4) cvt4(Wx, wx_bf, id);
            else *(short4v*)(wx_bf + (size_t)id * 4) = (short4v){0, 0, 0, 0};
            return;
        }
        id -= S1 / 4;
        if (id < S2 / 4) { cvt4(Wdt, wdt_bf, id); return; }
        id -= S2 / 4;
        if (id < S3 / 4) { cvt4(Wout, wout_bf, id); return; }
        id -= S3 / 4;
        *(floatx4*)(dbl + (size_t)id * 4) = (floatx4){0.f, 0.f, 0.f, 0.f};
    }
}

// ===== bf16 MFMA GEMM, compile-time-specialized epilogues (R17-proven) =======
// EPI: 3=atomicAdd (split-K, cheap per R24 postmortem); 5=softplus bf16.
#define GTM 128
#define GTN 128
#define GTK 32

template <int EPI>
__global__ __launch_bounds__(256) void gemm_t(
    const bf16* __restrict__ A, int lda,
    const bf16* __restrict__ B, int ldb,
    float* __restrict__ C, int ldc,
    int N, int K,
    const float* __restrict__ bias,
    bf16* __restrict__ C2)
{
    __shared__ short As[GTM * GTK];   // 8 KB
    __shared__ short Bs[GTN * GTK];   // 8 KB
    const int tid  = threadIdx.x;
    const int lane = tid & 63;
    const int wave = tid >> 6;            // 0..3
    const int wm = (wave & 1) * 64;
    const int wn = (wave >> 1) * 64;
    const int bm = blockIdx.y * GTM;
    const int bn = blockIdx.x * GTN;
    const int kbase = blockIdx.z * K;     // split-K base (K = slice length)

    floatx4 acc[4][4];
#pragma unroll
    for (int i = 0; i < 4; ++i)
#pragma unroll
        for (int j = 0; j < 4; ++j) acc[i][j] = (floatx4){0.f, 0.f, 0.f, 0.f};

    const int srow = wave * 16 + (lane >> 2);   // 0..63 (per pass)
    const int scol = (lane & 3) * 8;            // bf16 col within k-tile
    const int fm = lane & 15;
    const int q  = lane >> 4;

    for (int k0 = 0; k0 < K; k0 += GTK) {
#pragma unroll
        for (int r = 0; r < 2; ++r) {
            const int m = r * 64 + srow;
            gload16(A + (size_t)(bm + m) * lda + kbase + k0 + scol,
                    As + m * GTK + scol);
            gload16(B + (size_t)(bn + m) * ldb + kbase + k0 + scol,
                    Bs + m * GTK + scol);
        }
        __syncthreads();

        short8 af[4], bfr[4];
#pragma unroll
        for (int i = 0; i < 4; ++i)
            af[i] = *(short8*)&As[(wm + i * 16 + fm) * GTK + q * 8];
#pragma unroll
        for (int j = 0; j < 4; ++j)
            bfr[j] = *(short8*)&Bs[(wn + j * 16 + fm) * GTK + q * 8];
#pragma unroll
        for (int i = 0; i < 4; ++i)
#pragma unroll
            for (int j = 0; j < 4; ++j)
                acc[i][j] = __builtin_amdgcn_mfma_f32_16x16x32_bf16(
                    af[i], bfr[j], acc[i][j], 0, 0, 0);
        __syncthreads();
    }

    // C/D layout: col=lane&15, row=(lane>>4)*4+reg  [m89/m91-verified]
    const int col = lane & 15;
    const int rq  = (lane >> 4) * 4;
#pragma unroll
    for (int i = 0; i < 4; ++i) {
#pragma unroll
        for (int j = 0; j < 4; ++j) {
#pragma unroll
            for (int r = 0; r < 4; ++r) {
                const int gm = bm + wm + i * 16 + rq + r;
                const int gn = bn + wn + j * 16 + col;
                if (gn >= N) continue;
                float v = acc[i][j][r];
                if constexpr (EPI == 3) {
                    atomicAdd(&C[(size_t)gm * ldc + gn], v);
                } else if constexpr (EPI == 4) {
                    if (gn < D_INNER) C[(size_t)gm * ldc + gn] = v;
                    else C2[(size_t)gm * (size_t)D_INNER + (gn - D_INNER)] = f2b(v);
                } else {  // EPI == 5
                    C2[(size_t)gm * ldc + gn] = f2b(fsoftp(v + bias[gn]));
                }
            }
        }
    }
}

// ===== R25/R26: G2 as 256x128 / BK=32 / 2-blocks-per-CU counted-vmcnt ========
// R25 verified the occupancy+traffic model (Occ 17->32%, FETCH 38.7 MB) but
// left a 4-way LDS bank conflict: 4,194,304 conflict-cycles = exactly +4
// cyc per ds_read_b128. Cause: BK=32 rows are 64 B (bank-phase period = 2
// rows) and mask (fm&3) is constant over fm,fm+4,fm+8,fm+12 -> lanes in the
// same 8-lane phase hit identical bank quads. R26 fix: mask(row) =
// (row&3)^((row>>2)&3) -> enumerated lanes 0-7/8-15 cover all 32 banks.
// Applied BOTH sides (pre-swizzled source + read; rule #21); block offsets
// (wm*64, rf*16, +128-row pass) are ≡0 mod 16 so the fm-only read mask is
// exact.
#define UNT (D_MODEL / 32)     // 32 K-tiles

__global__ __launch_bounds__(512, 4) void gemm_uz2(
    const bf16* __restrict__ A,   // xn_bf [4096 x 1024]
    const bf16* __restrict__ B,   // win_bf [4096 x 1024]
    float* __restrict__ U,        // uraw  [4096 x 2048]
    bf16* __restrict__ Z)         // zbf   [4096 x 2048]
{
    // A: dbuf d at d*8192 shorts (256 x 32); B: 16384 + d*4096 (128 x 32).
    __shared__ __attribute__((aligned(16))) short lds[24576];   // 48 KiB
    const int t    = threadIdx.x;
    const int lane = t & 63;
    const int wid  = t >> 6;        // 0..7
    const int wm   = wid >> 1;      // 0..3: 64-row block of the 256-row tile
    const int wn   = wid & 1;       // 0..1: 64-col half of the 128-col tile
    const int fm   = lane & 15;
    const int q    = lane >> 4;

    // bijective XCD swizzle: 512 blocks; XCD j gets 64 consecutive nids =
    // 2 bm-panels x 32 bn -> A panels (1 MB) L2-resident per XCD.
    const int lin = (int)blockIdx.x;
    const int nid = (lin & 7) * 64 + (lin >> 3);
    const int bm  = (nid >> 5) * 256;
    const int bn  = (nid & 31) * 128;

    // staging: thread t covers tile-row (t>>2)+p*128, slot (t&3);
    // global col-slot pre-swizzled with R26 mask: (t&3)^(row&3)^((row>>2)&3)
    const int sg = (((t & 3) ^ ((t >> 2) & 3) ^ ((t >> 4) & 3)) << 3);  // shorts
    const short* Agp = (const short*)A + (size_t)(bm + (t >> 2)) * D_MODEL + sg;
    const short* Bgp = (const short*)B + (size_t)(bn + (t >> 2)) * D_MODEL + sg;

#define USTG(koff, d) do { \
        gload16(Agp + (koff),                        &lds[(d) * 8192 + t * 8]);        \
        gload16(Agp + (size_t)128 * D_MODEL + (koff), &lds[(d) * 8192 + 4096 + t * 8]); \
        gload16(Bgp + (koff),                        &lds[16384 + (d) * 4096 + t * 8]); \
    } while (0)

    // fragment-read swizzled slot (shorts): slot = q ^ (fm&3) ^ ((fm>>2)&3)
    const int ss = ((q ^ (fm & 3) ^ ((fm >> 2) & 3)) << 3);

    floatx4 acc[4][4];
#pragma unroll
    for (int i = 0; i < 4; ++i)
#pragma unroll
        for (int j = 0; j < 4; ++j) acc[i][j] = (floatx4){0.f, 0.f, 0.f, 0.f};

    // prologue: stage K-tile 0 into dbuf 0 (3 loads)
    USTG(0, 0);

    for (int kt = 0; kt < UNT; ++kt) {
        const int d = kt & 1;
        if (kt + 1 < UNT) {
            USTG((kt + 1) * 32, d ^ 1);
            asm volatile("s_waitcnt vmcnt(3)" ::: "memory");   // tile kt staged
        } else {
            asm volatile("s_waitcnt vmcnt(0)" ::: "memory");
        }
        __builtin_amdgcn_s_barrier();    // block-wide: tile kt fully staged

        const short* Ab = &lds[d * 8192 + wm * 2048];           // 64 rows x 32
        const short* Bb = &lds[16384 + d * 4096 + wn * 2048];   // 64 rows x 32

        short8 af[4], bfr[4];
#pragma unroll
        for (int rf = 0; rf < 4; ++rf)
            af[rf] = *(const short8*)(Ab + (rf * 16 + fm) * 32 + ss);
#pragma unroll
        for (int cf = 0; cf < 4; ++cf)
            bfr[cf] = *(const short8*)(Bb + (cf * 16 + fm) * 32 + ss);

        __builtin_amdgcn_s_setprio(1);
#pragma unroll
        for (int rf = 0; rf < 4; ++rf)
#pragma unroll
            for (int cf = 0; cf < 4; ++cf)
                acc[rf][cf] = __builtin_amdgcn_mfma_f32_16x16x32_bf16(
                    af[rf], bfr[cf], acc[rf][cf], 0, 0, 0);
        __builtin_amdgcn_s_setprio(0);
        __builtin_amdgcn_s_barrier();    // guards next iter's dbuf overwrite
    }
#undef USTG

    // epilogue: C/D layout col=lane&15, row=(lane>>4)*4+reg; u/z split.
    // bn blocks are 128-wide and D_INNER%128==0 -> block never straddles.
    const int gm0 = bm + wm * 64 + q * 4;
    const int gn0 = bn + wn * 64 + fm;
    if (bn < D_INNER) {          // u half -> fp32
#pragma unroll
        for (int rf = 0; rf < 4; ++rf)
#pragma unroll
            for (int cf = 0; cf < 4; ++cf)
#pragma unroll
                for (int r = 0; r < 4; ++r)
                    U[(size_t)(gm0 + rf * 16 + r) * D_INNER + gn0 + cf * 16] =
                        acc[rf][cf][r];
    } else {                     // z half -> bf16
#pragma unroll
        for (int rf = 0; rf < 4; ++rf)
#pragma unroll
            for (int cf = 0; cf < 4; ++cf)
#pragma unroll
                for (int r = 0; r < 4; ++r)
                    Z[(size_t)(gm0 + rf * 16 + r) * D_INNER + gn0 + cf * 16 - D_INNER] =
                        f2b(acc[rf][cf][r]);
    }
}

// ===== R20/R21: G7-dedicated GEMM, counted-vmcnt deep pipeline ===============
// KEPT: 64 KiB LDS, 52 VGPR -> 2 blocks/CU; counted vmcnt(4) proven here.
#define ONT (D_INNER / 64)     // 32 K-tiles

__global__ __launch_bounds__(512, 2) void gemm_out8(
    const bf16* __restrict__ A,   // ucy [4096 x 2048]
    const bf16* __restrict__ B,   // wout_bf [1024 x 2048]
    const float* __restrict__ resid,
    float* __restrict__ C)        // out [4096 x 1024] fp32
{
    __shared__ __attribute__((aligned(16))) short lds[32768];
    const int t    = threadIdx.x;
    const int lane = t & 63;
    const int wid  = t >> 6;        // 0..7
    const int wm   = wid >> 2;
    const int wn   = wid & 3;
    const int fm   = lane & 15;
    const int q    = lane >> 4;

    const int lin = (int)blockIdx.x;
    const int nid = (lin & 7) * 32 + (lin >> 3);
    const int bm  = (nid >> 3) * 128;
    const int bn  = (nid & 7) * 128;

    const int sg   = (((t & 7) ^ ((t >> 3) & 7)) << 3);
    const int ldst = t * 8;
    const short* Agp = (const short*)A + (size_t)(bm + (t >> 3)) * D_INNER + sg;
    const short* Bgp = (const short*)B + (size_t)(bn + (t >> 3)) * D_INNER + sg;

#define OSTG(g, lb) do { \
        gload16((g),                        &lds[(lb) + ldst]);        \
        gload16((g) + (size_t)64 * D_INNER, &lds[(lb) + 4096 + ldst]); \
    } while (0)

    const int ss0 = ((q ^ (fm & 7)) << 3);
    const int ss1 = (((4 + q) ^ (fm & 7)) << 3);
    const int fro = fm * 64;

    floatx4 acc[4][2];
#pragma unroll
    for (int i = 0; i < 4; ++i)
#pragma unroll
        for (int j = 0; j < 2; ++j) acc[i][j] = (floatx4){0.f, 0.f, 0.f, 0.f};

    OSTG(Agp, 0);
    OSTG(Bgp, 16384);

    for (int kt = 0; kt < ONT; ++kt) {
        const int d = kt & 1;
        if (kt + 1 < ONT) {
            const int kn = (kt + 1) * 64;
            const int nb = (d ^ 1) * 8192;
            OSTG(Agp + kn, nb);
            OSTG(Bgp + kn, 16384 + nb);
            asm volatile("s_waitcnt vmcnt(4)" ::: "memory");
        } else {
            asm volatile("s_waitcnt vmcnt(0)" ::: "memory");
        }
        __builtin_amdgcn_s_barrier();

        const short* Ab = &lds[d * 8192 + wm * 4096];
        const short* Bb = &lds[16384 + d * 8192 + wn * 2048];

        short8 bfr[2][2];
#pragma unroll
        for (int cf = 0; cf < 2; ++cf) {
            bfr[cf][0] = *(const short8*)(Bb + cf * 1024 + fro + ss0);
            bfr[cf][1] = *(const short8*)(Bb + cf * 1024 + fro + ss1);
        }

#pragma unroll
        for (int qd = 0; qd < 2; ++qd) {
            short8 af[2][2];
#pragma unroll
            for (int i = 0; i < 2; ++i) {
                af[i][0] = *(const short8*)(Ab + (qd * 2 + i) * 1024 + fro + ss0);
                af[i][1] = *(const short8*)(Ab + (qd * 2 + i) * 1024 + fro + ss1);
            }
            __builtin_amdgcn_s_barrier();
            __builtin_amdgcn_s_setprio(1);
#pragma unroll
            for (int i = 0; i < 2; ++i)
#pragma unroll
                for (int cf = 0; cf < 2; ++cf) {
                    acc[qd * 2 + i][cf] = __builtin_amdgcn_mfma_f32_16x16x32_bf16(
                        af[i][0], bfr[cf][0], acc[qd * 2 + i][cf], 0, 0, 0);
                    acc[qd * 2 + i][cf] = __builtin_amdgcn_mfma_f32_16x16x32_bf16(
                        af[i][1], bfr[cf][1], acc[qd * 2 + i][cf], 0, 0, 0);
                }
            __builtin_amdgcn_s_setprio(0);
            __builtin_amdgcn_s_barrier();
        }
    }
#undef OSTG

    const int gm0 = bm + wm * 64 + q * 4;
    const int gn0 = bn + wn * 32 + fm;
#pragma unroll
    for (int i = 0; i < 4; ++i)
#pragma unroll
        for (int cf = 0; cf < 2; ++cf)
#pragma unroll
            for (int r = 0; r < 4; ++r) {
                const size_t idx = (size_t)(gm0 + i * 16 + r) * D_MODEL + gn0 + cf * 16;
                C[idx] = acc[i][cf][r] + resid[idx];
            }
}

// ===== R20 conv+SiLU v2: rolling-window, float4, each element read once ======
#define CCH 128               // time chunks
#define CTC (LL / CCH)        // 16 steps per chunk

__global__ __launch_bounds__(256) void conv_v2(
    const float* __restrict__ uraw, const float* __restrict__ cw,
    const float* __restrict__ cb, bf16* __restrict__ ucb)
{
    const int blk = blockIdx.x;
    const int c  = blk & (CCH - 1);
    const int dg = (blk >> 7) & 1;
    const int b  = blk >> 8;
    const int d4 = dg * 1024 + threadIdx.x * 4;
    float w0[4], w1[4], w2[4], w3[4], bias[4];
#pragma unroll
    for (int j = 0; j < 4; ++j) {
        bias[j] = cb[d4 + j];
        w0[j] = cw[(d4 + j) * 4 + 0];
        w1[j] = cw[(d4 + j) * 4 + 1];
        w2[j] = cw[(d4 + j) * 4 + 2];
        w3[j] = cw[(d4 + j) * 4 + 3];
    }
    const size_t base = ((size_t)b * LL + (size_t)c * CTC) * D_INNER + d4;
    floatx4 x0 = {0.f, 0.f, 0.f, 0.f}, x1 = x0, x2 = x0;
    if (c > 0) {
        x0 = *(const floatx4*)(uraw + base - 3 * (size_t)D_INNER);
        x1 = *(const floatx4*)(uraw + base - 2 * (size_t)D_INNER);
        x2 = *(const floatx4*)(uraw + base - 1 * (size_t)D_INNER);
    }
#pragma unroll
    for (int tt = 0; tt < CTC; ++tt) {
        const floatx4 x3 = *(const floatx4*)(uraw + base + (size_t)tt * D_INNER);
        short4v o;
#pragma unroll
        for (int j = 0; j < 4; ++j) {
            float a = bias[j] + x0[j] * w0[j] + x1[j] * w1[j]
                              + x2[j] * w2[j] + x3[j] * w3[j];
            a = a * fsig(a);
            bf16 h = f2b(a);
            unsigned short us;
            __builtin_memcpy(&us, &h, 2);
            o[j] = (short)us;
        }
        *(short4v*)(ucb + base + (size_t)tt * D_INNER) = o;
        x0 = x1; x1 = x2; x2 = x3;
    }
}

// ------------- dbl[:, :64] -> bf16 dt_r copy for GEMM-5 ----------------------
__global__ __launch_bounds__(256) void cvt_dtr(
    const float* __restrict__ dbl, bf16* __restrict__ dtr_bf)
{
    const int id = blockIdx.x * 256 + threadIdx.x;  // m*64+r
    const int m = id >> 6, r = id & 63;
    dtr_bf[id] = f2b(dbl[(size_t)m * DBL_LD + r]);
}

// ------------------------------ 3-phase scan ---------------------------------
__global__ __launch_bounds__(256) void scan_p1(
    const bf16* __restrict__ uc, const bf16* __restrict__ dtb,
    const float* __restrict__ dbl, const float* __restrict__ A_log,
    float* __restrict__ Psum, float* __restrict__ Hloc)
{
    const int blk = blockIdx.x;
    const int d = (blk & 7) * 256 + threadIdx.x;
    const int c = (blk >> 3) & (NCH - 1);
    const int b = blk >> 9;                  // NCH=64 -> 9 bits below b
    float A[D_STATE], h[D_STATE];
    bool lin = true;
#pragma unroll
    for (int n = 0; n < D_STATE; ++n) {
        A[n] = -__expf(A_log[d * D_STATE + n]);
        lin = lin && (fabsf(A[n] + (float)(n + 1)) < 1e-3f);
        h[n] = 0.f;
    }
    const size_t row0 = (size_t)b * LL + c * TCH;
    const bf16* dtp = dtb + row0 * D_INNER + d;
    const bf16* up  = uc  + row0 * D_INNER + d;
    const float* Bp = dbl + row0 * DBL_LD + DT_RANK;
    float S = 0.f;
    if (lin) {
        for (int t = 0; t < TCH; ++t) {
            const float dtv = (float)dtp[(size_t)t * D_INNER];
            const float uv  = (float)up[(size_t)t * D_INNER];
            const float du  = dtv * uv;
            S += dtv;
            const float e1 = __expf(-dtv);
            float dA = 1.f;
#pragma unroll
            for (int n = 0; n < D_STATE; ++n) {
                dA *= e1;                       // e1^(n+1)
                h[n] = dA * h[n] + du * Bp[(size_t)t * DBL_LD + n];
            }
        }
    } else {
        for (int t = 0; t < TCH; ++t) {
            const float dtv = (float)dtp[(size_t)t * D_INNER];
            const float uv  = (float)up[(size_t)t * D_INNER];
            const float du  = dtv * uv;
            S += dtv;
#pragma unroll
            for (int n = 0; n < D_STATE; ++n)
                h[n] = __expf(dtv * A[n]) * h[n] + du * Bp[(size_t)t * DBL_LD + n];
        }
    }
    const size_t o = (((size_t)b * NCH + c) * D_INNER + d) * D_STATE;
    if (lin) {
        const float E1 = __expf(-S);
        float P = 1.f;
#pragma unroll
        for (int n = 0; n < D_STATE; ++n) {
            P *= E1;
            Psum[o + n] = P;
            Hloc[o + n] = h[n];
        }
    } else {
#pragma unroll
        for (int n = 0; n < D_STATE; ++n) {
            Psum[o + n] = __expf(S * A[n]);
            Hloc[o + n] = h[n];
        }
    }
}

__global__ __launch_bounds__(256) void scan_p2(
    float* __restrict__ Psum, const float* __restrict__ Hloc)
{
    const int id = blockIdx.x * 256 + threadIdx.x;
    const int dn = id & (D_INNER * D_STATE - 1);
    const int b  = id >> 15;
    float h = 0.f;
    for (int c = 0; c < NCH; ++c) {
        const size_t o = ((size_t)(b * NCH + c) * D_INNER * D_STATE) + dn;
        const float P  = Psum[o];
        const float hl = Hloc[o];
        Psum[o] = h;          // Hin for chunk c
        h = P * h + hl;
    }
}

// phase 3: replay; bf16 u (ucy), bf16 dt, bf16 z (zbf); y overwrites ucy
__global__ __launch_bounds__(256) void scan_p3b(
    bf16* __restrict__ ucy, const bf16* __restrict__ dtb,
    const float* __restrict__ dbl, const float* __restrict__ A_log,
    const float* __restrict__ Dw, const float* __restrict__ Hin,
    const bf16* __restrict__ zbf)
{
    const int blk = blockIdx.x;
    const int d = (blk & 7) * 256 + threadIdx.x;
    const int c = (blk >> 3) & (NCH - 1);
    const int b = blk >> 9;                  // NCH=64 -> 9 bits below b
    float A[D_STATE], h[D_STATE];
    const size_t o = (((size_t)b * NCH + c) * D_INNER + d) * D_STATE;
    bool lin = true;
#pragma unroll
    for (int n = 0; n < D_STATE; ++n) {
        A[n] = -__expf(A_log[d * D_STATE + n]);
        lin = lin && (fabsf(A[n] + (float)(n + 1)) < 1e-3f);
        h[n] = Hin[o + n];
    }
    const float Dd = Dw[d];
    const size_t row0 = (size_t)b * LL + c * TCH;
    const bf16* dtp = dtb + row0 * D_INNER + d;
    bf16*       uyp = ucy + row0 * D_INNER + d;     // u in, y out (same slot)
    const float* BCp = dbl + row0 * DBL_LD;
    const bf16* zp   = zbf + row0 * D_INNER + d;
    if (lin) {
        for (int t = 0; t < TCH; ++t) {
            const float dtv = (float)dtp[(size_t)t * D_INNER];
            const float uv  = (float)uyp[(size_t)t * D_INNER];
            const float du  = dtv * uv;
            float acc = uv * Dd;
            const float* Brow = BCp + (size_t)t * DBL_LD + DT_RANK;
            const float* Crow = Brow + D_STATE;
            const float e1 = __expf(-dtv);
            float dA = 1.f;
#pragma unroll
            for (int n = 0; n < D_STATE; ++n) {
                dA *= e1;                       // e1^(n+1)
                h[n] = dA * h[n] + du * Brow[n];
                acc += h[n] * Crow[n];
            }
            const float zv = (float)zp[(size_t)t * D_INNER];
            uyp[(size_t)t * D_INNER] = f2b(acc * zv * fsig(zv));
        }
    } else {
        for (int t = 0; t < TCH; ++t) {
            const float dtv = (float)dtp[(size_t)t * D_INNER];
            const float uv  = (float)uyp[(size_t)t * D_INNER];
            const float du  = dtv * uv;
            float acc = uv * Dd;
            const float* Brow = BCp + (size_t)t * DBL_LD + DT_RANK;
            const float* Crow = Brow + D_STATE;
#pragma unroll
            for (int n = 0; n < D_STATE; ++n) {
                h[n] = __expf(dtv * A[n]) * h[n] + du * Brow[n];
                acc += h[n] * Crow[n];
            }
            const float zv = (float)zp[(size_t)t * D_INNER];
            uyp[(size_t)t * D_INNER] = f2b(acc * zv * fsig(zv));
        }
    }
}

// ---------------- fallback (small ws): R4 sequential path --------------------
#define BM 128
#define BN 128
#define BK 8

__global__ __launch_bounds__(256) void ln_kernel(
    const float* __restrict__ x, const float* __restrict__ w,
    const float* __restrict__ b, float* __restrict__ xnf)
{
    __shared__ float s1[256], s2[256];
    const int row = blockIdx.x;
    const int tid = threadIdx.x;
    const float* xr = x + (size_t)row * D_MODEL;
    float v[4], sum = 0.f, sq = 0.f;
#pragma unroll
    for (int i = 0; i < 4; ++i) {
        v[i] = xr[tid + 256 * i];
        sum += v[i];
        sq  += v[i] * v[i];
    }
    s1[tid] = sum; s2[tid] = sq;
    __syncthreads();
    for (int s = 128; s > 0; s >>= 1) {
        if (tid < s) { s1[tid] += s1[tid + s]; s2[tid] += s2[tid + s]; }
        __syncthreads();
    }
    const float mu  = s1[0] * (1.f / D_MODEL);
    const float var = s2[0] * (1.f / D_MODEL) - mu * mu;
    const float rs  = rsqrtf(var + 1e-5f);
#pragma unroll
    for (int i = 0; i < 4; ++i) {
        const int c = tid + 256 * i;
        xnf[(size_t)row * D_MODEL + c] = (v[i] - mu) * rs * w[c] + b[c];
    }
}

__global__ __launch_bounds__(256) void gemm_bt(
    const float* __restrict__ A, int lda,
    const float* __restrict__ Bw,
    float* __restrict__ C, int ldc,
    int M, int N, int K, int epi,
    const float* __restrict__ bias,
    const float* __restrict__ resid)
{
    __shared__ float As[BK][BM + 1];
    __shared__ float Bs[BK][BN + 1];
    const int tx = threadIdx.x, ty = threadIdx.y;
    const int tid = ty * 16 + tx;
    const int bm = blockIdx.y * BM, bn = blockIdx.x * BN;
    float acc[8][8];
#pragma unroll
    for (int i = 0; i < 8; ++i)
#pragma unroll
        for (int j = 0; j < 8; ++j) acc[i][j] = 0.f;
    for (int k0 = 0; k0 < K; k0 += BK) {
#pragma unroll
        for (int i = tid; i < BM * BK; i += 256) {
            const int m = i / BK, kk = i % BK;
            As[kk][m] = A[(size_t)(bm + m) * lda + (k0 + kk)];
        }
#pragma unroll
        for (int i = tid; i < BN * BK; i += 256) {
            const int n = i / BK, kk = i % BK;
            const int gn = bn + n;
            Bs[kk][n] = (gn < N) ? Bw[(size_t)gn * K + (k0 + kk)] : 0.f;
        }
        __syncthreads();
#pragma unroll
        for (int kk = 0; kk < BK; ++kk) {
            float av[8], bv[8];
#pragma unroll
            for (int i = 0; i < 8; ++i) av[i] = As[kk][ty * 8 + i];
#pragma unroll
            for (int j = 0; j < 8; ++j) bv[j] = Bs[kk][tx * 8 + j];
#pragma unroll
            for (int i = 0; i < 8; ++i)
#pragma unroll
                for (int j = 0; j < 8; ++j) acc[i][j] += av[i] * bv[j];
        }
        __syncthreads();
    }
#pragma unroll
    for (int i = 0; i < 8; ++i) {
        const int gm = bm + ty * 8 + i;
#pragma unroll
        for (int j = 0; j < 8; ++j) {
            const int gn = bn + tx * 8 + j;
            if (gn >= N) continue;
            float v = acc[i][j];
            if (epi == 1) {
                v += bias[gn];
                v = fmaxf(v, 0.f) + log1pf(expf(-fabsf(v)));
            } else if (epi == 2) {
                v += resid[(size_t)gm * ldc + gn];
            }
            C[(size_t)gm * ldc + gn] = v;
        }
    }
}

__global__ __launch_bounds__(256) void conv_silu_kernel(
    float* __restrict__ xz, const float* __restrict__ cw,
    const float* __restrict__ cb)
{
    const int idx = blockIdx.x * 256 + threadIdx.x;
    const int b = idx >> 11, d = idx & (D_INNER - 1);
    const float w0 = cw[d * 4 + 0], w1 = cw[d * 4 + 1];
    const float w2 = cw[d * 4 + 2], w3 = cw[d * 4 + 3];
    const float bias = cb[d];
    float* u = xz + (size_t)b * LL * XZ_LD + d;
    float x0 = 0.f, x1 = 0.f, x2 = 0.f;
    for (int t = 0; t < LL; ++t) {
        const float x3 = u[(size_t)t * XZ_LD];
        const float c = bias + x0 * w0 + x1 * w1 + x2 * w2 + x3 * w3;
        u[(size_t)t * XZ_LD] = c / (1.f + expf(-c));
        x0 = x1; x1 = x2; x2 = x3;
    }
}

__global__ __launch_bounds__(256) void scan_kernel(
    float* __restrict__ xz, const float* __restrict__ dtb,
    const float* __restrict__ dbl,
    const float* __restrict__ A_log, const float* __restrict__ Dw)
{
    const int idx = blockIdx.x * 256 + threadIdx.x;
    const int b = idx >> 11, d = idx & (D_INNER - 1);
    float A[D_STATE], h[D_STATE];
#pragma unroll
    for (int n = 0; n < D_STATE; ++n) {
        A[n] = -expf(A_log[d * D_STATE + n]);
        h[n] = 0.f;
    }
    const float Dd = Dw[d];
    const float* dtp  = dtb + (size_t)b * LL * D_INNER + d;
    float*       up   = xz  + (size_t)b * LL * XZ_LD + d;
    const float* dblp = dbl + (size_t)b * LL * DBL_LD;
    for (int t = 0; t < LL; ++t) {
        const float dtv = dtp[(size_t)t * D_INNER];
        const float uv  = up[(size_t)t * XZ_LD];
        const float zv  = up[(size_t)t * XZ_LD + D_INNER];
        const float* Brow = dblp + (size_t)t * DBL_LD + DT_RANK;
        const float* Crow = Brow + D_STATE;
        const float du = dtv * uv;
        float acc = uv * Dd;
#pragma unroll
        for (int n = 0; n < D_STATE; ++n) {
            const float dA = expf(dtv * A[n]);
            h[n] = dA * h[n] + du * Brow[n];
            acc += h[n] * Crow[n];
        }
        const float sz = zv / (1.f + expf(-zv));
        up[(size_t)t * XZ_LD] = acc * sz;
    }
}

extern "C" void kernel_launch(void* const* d_in, const int* in_sizes, int n_in,
                              void* d_out, int out_size, void* d_ws, size_t ws_size,
                              hipStream_t stream)
{
    const float* x       = (const float*)d_in[0];
    const float* ln_w    = (const float*)d_in[1];
    const float* ln_b    = (const float*)d_in[2];
    const float* W_in    = (const float*)d_in[3];
    const float* conv_w  = (const float*)d_in[4];
    const float* conv_b  = (const float*)d_in[5];
    const float* W_xproj = (const float*)d_in[6];
    const float* W_dt    = (const float*)d_in[7];
    const float* b_dt    = (const float*)d_in[8];
    const float* A_log   = (const float*)d_in[9];
    const float* Dw      = (const float*)d_in[10];
    const float* W_out   = (const float*)d_in[11];
    float* out = (float*)d_out;

    // ws layout identical to R15-R18 (134.8 MiB, each size audited)
    float* wsf     = (float*)d_ws;
    bf16*  dtb_bf  = (bf16*)wsf;
    float* uraw    = wsf + 4194304;
    bf16*  zbf     = (bf16*)(wsf + 12582912);
    float* Psum    = wsf + 16777216;
    float* Hloc    = wsf + 20971520;
    float* dbl     = wsf + 25165824;
    bf16*  ucy     = (bf16*)(wsf + 25559040);
    bf16*  xn_bf   = (bf16*)(wsf + 29753344);
    bf16*  win_bf  = (bf16*)(wsf + 31850496);
    bf16*  wx_bf   = (bf16*)(wsf + 33947648);
    bf16*  wdt_bf  = (bf16*)(wsf + 34078720);
    bf16*  wout_bf = (bf16*)(wsf + 34144256);
    bf16*  dtr_bf  = (bf16*)(wsf + 35192832);
    const size_t need_big = (size_t)35323904 * sizeof(float);

    if (ws_size >= need_big) {
        // fused LN + vectorized weight cvt (+dbl zero) — one launch
        prep_kernel<<<BL + WCVT4 / 256, 256, 0, stream>>>(
            x, ln_w, ln_b, xn_bf,
            W_in, W_xproj, W_dt, W_out, win_bf, wx_bf, wdt_bf, wout_bf, dbl);
        // G2: [u|z] = xn @ W_in^T via 256x128/BK=32 kernel (R26 conflict-free)
        gemm_uz2<<<dim3(512), 512, 0, stream>>>(xn_bf, win_bf, uraw, zbf);
        // conv+SiLU v2: rolling-window float4, fp32 u -> bf16 uc
        conv_v2<<<BB * 2 * CCH, 256, 0, stream>>>(uraw, conv_w, conv_b, ucy);
        // G4: dbl += uc @ W_xproj^T  (N=96 pad 128, split-K=8)  [EPI=3 atomic]
        gemm_t<3><<<dim3(1, BL / GTM, 8), 256, 0, stream>>>(
            ucy, D_INNER, wx_bf, D_INNER, dbl, DBL_LD,
            DBL_LD, D_INNER / 8, nullptr, nullptr);
        cvt_dtr<<<BL * DT_RANK / 256, 256, 0, stream>>>(dbl, dtr_bf);
        // G5: dt = softplus(dt_r @ W_dt^T + b_dt), bf16 store  [EPI=5]
        gemm_t<5><<<dim3(D_INNER / GTN, BL / GTM, 1), 256, 0, stream>>>(
            dtr_bf, DT_RANK, wdt_bf, DT_RANK, nullptr, D_INNER,
            D_INNER, DT_RANK, b_dt, dtb_bf);
        // chunked scan, NCH=64 (exp-power fast path)
        scan_p1<<<BB * NCH * 8, 256, 0, stream>>>(
            ucy, dtb_bf, dbl, A_log, Psum, Hloc);
        scan_p2<<<BB * D_INNER * D_STATE / 256, 256, 0, stream>>>(Psum, Hloc);
        scan_p3b<<<BB * NCH * 8, 256, 0, stream>>>(
            ucy, dtb_bf, dbl, A_log, Dw, Psum, zbf);
        // G7: out = y @ W_out^T + x  via counted-vmcnt 128x128 kernel
        gemm_out8<<<dim3(256), 512, 0, stream>>>(ucy, wout_bf, x, out);
    } else {
        float* fdtb = wsf;
        float* fxn  = fdtb;
        float* fxz  = fdtb + (size_t)BL * D_INNER;
        float* fdbl = fxz + (size_t)BL * XZ_LD;
        ln_kernel<<<BL, 256, 0, stream>>>(x, ln_w, ln_b, fxn);
        dim3 blk(16, 16);
        gemm_bt<<<dim3(XZ_LD / BN, BL / BM), blk, 0, stream>>>(
            fxn, D_MODEL, W_in, fxz, XZ_LD, BL, XZ_LD, D_MODEL, 0, nullptr, nullptr);
        conv_silu_kernel<<<(BB * D_INNER) / 256, 256, 0, stream>>>(fxz, conv_w, conv_b);
        gemm_bt<<<dim3(1, BL / BM), blk, 0, stream>>>(
            fxz, XZ_LD, W_xproj, fdbl, DBL_LD, BL, DBL_LD, D_INNER, 0, nullptr, nullptr);
        gemm_bt<<<dim3(D_INNER / BN, BL / BM), blk, 0, stream>>>(
            fdbl, DBL_LD, W_dt, fdtb, D_INNER, BL, D_INNER, DT_RANK, 1, b_dt, nullptr);
        scan_kernel<<<(BB * D_INNER) / 256, 256, 0, stream>>>(fxz, fdtb, fdbl, A_log, Dw);
        gemm_bt<<<dim3(D_MODEL / BN, BL / BM), blk, 0, stream>>>(
            fxz, XZ_LD, W_out, out, D_MODEL, BL, D_MODEL, D_INNER, 2, nullptr, x);
    }
}